// Round 1
// baseline (260.047 us; speedup 1.0000x reference)
//
#include <hip/hip_runtime.h>

// Modulated deformable conv (DCNv2) fwd, fp32 fused.
// B=8, C=64, H=W=96, O=64, K=3, stride=1, pad=1, dil=1, DG=1 -> Ho=Wo=96.
// Block = (batch b, tile of 64 consecutive output pixels), computes all 64
// output channels. Waves: lane = output channel o, wave id = 16-pixel group.

#define B_   8
#define C_   64
#define H_   96
#define W_   96
#define O_   64
#define KK_  9
#define HW_  (H_ * W_)          // 9216
#define PIXB 64                 // pixels per block
#define CCH  8                  // channels per chunk
#define NCH  (C_ / CCH)         // 8 chunks
#define NTILE (HW_ / PIXB)      // 144 tiles per image

// LDS (floats):
//   samp  [CCH*KK_][64]      = 4608
//   wlds  [CCH*KK_][65 pad]  = 4680   (wlds[q*65 + o])
//   c_ly/c_lx/c_mv [576], c_y0/c_x0 int [576]  = 2880
// total 12168 floats = 48672 B -> 3 blocks/CU (146 KB of 160 KB)

__global__ __launch_bounds__(256, 3)
void dcn_fused_f32(const float* __restrict__ x, const float* __restrict__ offs,
                   const float* __restrict__ mask, const float* __restrict__ wgt,
                   const float* __restrict__ bias, float* __restrict__ out)
{
    __shared__ float smem[12168];
    float* samp = smem;                  // 4608
    float* wlds = smem + 4608;           // 4680
    float* c_ly = wlds + 4680;           // 576
    float* c_lx = c_ly + 576;
    float* c_mv = c_lx + 576;
    int*   c_y0 = (int*)(c_mv + 576);
    int*   c_x0 = c_y0 + 576;

    const int t    = threadIdx.x;
    const int lane = t & 63;
    const int wid  = t >> 6;
    const int bi   = blockIdx.x / NTILE;
    const int tile = blockIdx.x % NTILE;
    const int pixbase = tile * PIXB;

    // ---- phase 1: sampling coords for (kk, p), 576 tasks ----
    for (int r = 0; r < 3; ++r) {
        int i = t + 256 * r;
        if (i < KK_ * PIXB) {
            int kk = i >> 6, p = i & 63;
            int pix = pixbase + p;
            int ho = pix / W_, wo = pix % W_;
            int ky = kk / 3, kx = kk % 3;
            float offy = offs[((size_t)bi * 18 + 2 * kk + 0) * HW_ + pix];
            float offx = offs[((size_t)bi * 18 + 2 * kk + 1) * HW_ + pix];
            float mv   = mask[((size_t)bi * 9 + kk) * HW_ + pix];
            float py = (float)(ho - 1 + ky) + offy;
            float px = (float)(wo - 1 + kx) + offx;
            float y0f = floorf(py), x0f = floorf(px);
            c_ly[i] = py - y0f;
            c_lx[i] = px - x0f;
            c_mv[i] = mv;
            c_y0[i] = (int)y0f;
            c_x0[i] = (int)x0f;
        }
    }

    float acc[16];
    #pragma unroll
    for (int j = 0; j < 16; ++j) acc[j] = 0.f;

    const int pbase = wid * 16;
    const float* xb = x + (size_t)bi * C_ * HW_;

    for (int ch = 0; ch < NCH; ++ch) {
        const int c0 = ch * CCH;
        __syncthreads();   // protect samp/wlds vs previous chunk's readers

        // ---- stage weight chunk, transposed to [q][o] ----
        #pragma unroll 3
        for (int r = 0; r < 18; ++r) {
            int j = t + 256 * r;              // 4608 values
            int o = j / 72, q = j % 72;       // q = cc*9 + kk
            wlds[q * 65 + o] = wgt[(size_t)o * (C_ * KK_) + c0 * 9 + q];
        }

        // ---- deformable bilinear sampling into samp[ck][p] ----
        #pragma unroll 3
        for (int r = 0; r < 18; ++r) {
            int i = t + 256 * r;              // 4608 values
            int ck = i >> 6, p = i & 63;
            int cc = ck / 9, kk = ck % 9;
            int ci = kk * 64 + p;
            float ly = c_ly[ci], lx = c_lx[ci], mv = c_mv[ci];
            int y0 = c_y0[ci], x0 = c_x0[ci];
            int y1 = y0 + 1,  x1 = x0 + 1;
            const float* xc = xb + (size_t)(c0 + cc) * HW_;
            bool yin0 = (y0 >= 0) & (y0 < H_);
            bool yin1 = (y1 >= 0) & (y1 < H_);
            bool xin0 = (x0 >= 0) & (x0 < W_);
            bool xin1 = (x1 >= 0) & (x1 < W_);
            float v00 = (yin0 & xin0) ? xc[y0 * W_ + x0] : 0.f;
            float v01 = (yin0 & xin1) ? xc[y0 * W_ + x1] : 0.f;
            float v10 = (yin1 & xin0) ? xc[y1 * W_ + x0] : 0.f;
            float v11 = (yin1 & xin1) ? xc[y1 * W_ + x1] : 0.f;
            float hy = 1.f - ly, hx = 1.f - lx;
            samp[i] = (v00 * hy * hx + v01 * hy * lx +
                       v10 * ly * hx + v11 * ly * lx) * mv;
        }
        __syncthreads();

        // ---- accumulate: lane = o, 16 pixels per wave ----
        #pragma unroll 4
        for (int q = 0; q < CCH * KK_; ++q) {
            float wv = wlds[q * 65 + lane];               // stride-1, conflict-free
            const float4* sp = (const float4*)&samp[q * 64 + pbase]; // wave-uniform
            float4 s0 = sp[0], s1 = sp[1], s2 = sp[2], s3 = sp[3];
            acc[0]  = fmaf(wv, s0.x, acc[0]);
            acc[1]  = fmaf(wv, s0.y, acc[1]);
            acc[2]  = fmaf(wv, s0.z, acc[2]);
            acc[3]  = fmaf(wv, s0.w, acc[3]);
            acc[4]  = fmaf(wv, s1.x, acc[4]);
            acc[5]  = fmaf(wv, s1.y, acc[5]);
            acc[6]  = fmaf(wv, s1.z, acc[6]);
            acc[7]  = fmaf(wv, s1.w, acc[7]);
            acc[8]  = fmaf(wv, s2.x, acc[8]);
            acc[9]  = fmaf(wv, s2.y, acc[9]);
            acc[10] = fmaf(wv, s2.z, acc[10]);
            acc[11] = fmaf(wv, s2.w, acc[11]);
            acc[12] = fmaf(wv, s3.x, acc[12]);
            acc[13] = fmaf(wv, s3.y, acc[13]);
            acc[14] = fmaf(wv, s3.z, acc[14]);
            acc[15] = fmaf(wv, s3.w, acc[15]);
        }
    }

    // ---- epilogue: LDS transpose for coalesced store ----
    __syncthreads();
    float* outb = smem;                   // [o][66] = 4224 floats, aliases samp
    #pragma unroll
    for (int j = 0; j < 16; ++j)
        outb[lane * 66 + pbase + j] = acc[j];
    __syncthreads();
    #pragma unroll
    for (int r = 0; r < 16; ++r) {
        int idx = t + 256 * r;            // 4096 outputs
        int o = idx >> 6, p = idx & 63;
        out[((size_t)bi * O_ + o) * HW_ + pixbase + p] = outb[o * 66 + p] + bias[o];
    }
}

extern "C" void kernel_launch(void* const* d_in, const int* in_sizes, int n_in,
                              void* d_out, int out_size, void* d_ws, size_t ws_size,
                              hipStream_t stream)
{
    const float* x    = (const float*)d_in[0];
    const float* offs = (const float*)d_in[1];
    const float* mask = (const float*)d_in[2];
    const float* wgt  = (const float*)d_in[3];
    const float* bias = (const float*)d_in[4];
    float* out = (float*)d_out;

    dim3 grid(B_ * NTILE);   // 1152
    dim3 block(256);
    hipLaunchKernelGGL(dcn_fused_f32, grid, block, 0, stream,
                       x, offs, mask, wgt, bias, out);
}

// Round 2
// 203.359 us; speedup vs baseline: 1.2788x; 1.2788x over previous
//
#include <hip/hip_runtime.h>

// Modulated deformable conv (DCNv2) fwd — bf16-MFMA fused version.
// B=8, C=64, H=W=96, O=64, K=3, stride=1, pad=1, dil=1, DG=1 -> Ho=Wo=96.
// Block = (batch, 64 consecutive output pixels), computes all 64 output
// channels via 4 waves x (32o x 32px) MFMA tiles. K = C*KK = 576, chunked
// by kernel position kk (chunk K = 64 channels) so sampling coords are
// computed once per (kk, pixel) and reused across all channels.

#define B_   8
#define C_   64
#define H_   96
#define W_   96
#define O_   64
#define KK_  9
#define HW_  (H_ * W_)          // 9216
#define PIXB 64
#define NTILE (HW_ / PIXB)      // 144

typedef __attribute__((ext_vector_type(8))) short short8;   // 8 bf16 = 4 VGPR
typedef __attribute__((ext_vector_type(4))) float f32x4;

__device__ __forceinline__ unsigned short f2bf(float f) {
    union { float f; unsigned u; } v; v.f = f;
    unsigned r = v.u + 0x7FFF + ((v.u >> 16) & 1);   // RNE
    return (unsigned short)(r >> 16);
}

// ---- pre-kernel: weights fp32 [O][C][KK] -> bf16 ws [kk][o][c] ----
__global__ void cvt_w_kernel(const float* __restrict__ wgt,
                             unsigned short* __restrict__ wsb) {
    int i = blockIdx.x * 256 + threadIdx.x;          // (o,c)
    if (i < O_ * C_) {
        int o = i >> 6, c = i & 63;
        #pragma unroll
        for (int kk = 0; kk < KK_; ++kk)
            wsb[kk * (O_ * C_) + o * C_ + c] =
                f2bf(wgt[(size_t)(o * C_ + c) * KK_ + kk]);
    }
}

// LDS: samp 8192 B ([64 px rows][128 B bf16, XOR-swizzled])
//      wl   8192 B ([64 o rows][128 B bf16, XOR-swizzled])
//      coords 576*20 B = 11520
// total 27904 B -> 4 blocks/CU (LDS would allow 5; VGPR/launch_bounds -> 4)
__global__ __launch_bounds__(256, 4)
void dcn_mfma(const float* __restrict__ x, const float* __restrict__ offs,
              const float* __restrict__ mask,
              const unsigned short* __restrict__ wsb,
              const float* __restrict__ bias, float* __restrict__ out)
{
    __shared__ __align__(16) char lds[27904];
    char*  samp = lds;                       // 8192
    char*  wl   = lds + 8192;                // 8192
    float* c_ly = (float*)(lds + 16384);
    float* c_lx = c_ly + 576;
    float* c_mv = c_lx + 576;
    int*   c_y0 = (int*)(c_mv + 576);
    int*   c_x0 = c_y0 + 576;

    const int t    = threadIdx.x;
    const int lane = t & 63;
    const int wid  = t >> 6;
    const int bi   = blockIdx.x / NTILE;
    const int tile = blockIdx.x % NTILE;
    const int pixbase = tile * PIXB;

    // ---- phase 1: sampling coords for (kk, p): 576 entries ----
    #pragma unroll
    for (int r = 0; r < 3; ++r) {
        int i = t + 256 * r;
        if (i < KK_ * PIXB) {
            int kk = i >> 6, p = i & 63;
            int pix = pixbase + p;
            int ho = pix / W_, wo = pix % W_;
            float offy = offs[((size_t)bi * 18 + 2 * kk + 0) * HW_ + pix];
            float offx = offs[((size_t)bi * 18 + 2 * kk + 1) * HW_ + pix];
            float mv   = mask[((size_t)bi * 9 + kk) * HW_ + pix];
            float py = (float)(ho - 1 + kk / 3) + offy;
            float px = (float)(wo - 1 + kk % 3) + offx;
            float y0f = floorf(py), x0f = floorf(px);
            c_ly[i] = py - y0f;
            c_lx[i] = px - x0f;
            c_mv[i] = mv;
            c_y0[i] = (int)y0f;
            c_x0[i] = (int)x0f;
        }
    }

    f32x4 acc[2][2] = {};
    const int wr = wid >> 1, wc = wid & 1;     // wave -> (o half, px half)
    const int lr = lane & 15, lg = lane >> 4;

    const float* xb  = x + (size_t)bi * C_ * HW_;
    const int p_s = lane;                       // this thread's sample pixel
    const int cg  = wid;                        // channel group: cg*16..+15
    const float* xc0 = xb + (size_t)cg * 16 * HW_;

    for (int kk = 0; kk < KK_; ++kk) {
        __syncthreads();   // coords ready (kk==0) / prev chunk consumed

        // ---- stage W chunk kk: [o][c] bf16, swizzled ----
        {
            int o = t >> 2, cq = (t & 3) * 16;  // 16 bf16 = 32 B per thread
            const uint4* g = (const uint4*)(wsb + (size_t)kk * (O_ * C_)
                                            + o * C_ + cq);
            uint4 w0 = g[0], w1 = g[1];
            char* base = wl + o * 128;
            int s = (o & 7) << 4;
            *(uint4*)(base + ((cq * 2) ^ s))      = w0;
            *(uint4*)(base + ((cq * 2 + 16) ^ s)) = w1;
        }

        // ---- sample 16 channels of pixel p_s, pack bf16, swizzled write ----
        {
            int ci = kk * 64 + p_s;
            float ly = c_ly[ci], lx = c_lx[ci], mv = c_mv[ci];
            int y0 = c_y0[ci], x0 = c_x0[ci];
            int y1 = y0 + 1, x1 = x0 + 1;
            float hy = 1.f - ly, hx = 1.f - lx;
            bool oky0 = (y0 >= 0) & (y0 < H_), oky1 = (y1 >= 0) & (y1 < H_);
            bool okx0 = (x0 >= 0) & (x0 < W_), okx1 = (x1 >= 0) & (x1 < W_);
            float w00 = hy * hx * mv * ((oky0 & okx0) ? 1.f : 0.f);
            float w01 = hy * lx * mv * ((oky0 & okx1) ? 1.f : 0.f);
            float w10 = ly * hx * mv * ((oky1 & okx0) ? 1.f : 0.f);
            float w11 = ly * lx * mv * ((oky1 & okx1) ? 1.f : 0.f);
            int iy0 = min(max(y0, 0), H_ - 1), iy1 = min(max(y1, 0), H_ - 1);
            int ix0 = min(max(x0, 0), W_ - 1), ix1 = min(max(x1, 0), W_ - 1);
            int i00 = iy0 * W_ + ix0, i01 = iy0 * W_ + ix1;
            int i10 = iy1 * W_ + ix0, i11 = iy1 * W_ + ix1;

            union { unsigned u[8]; uint4 v[2]; } pk;
            const float* xc = xc0;
            #pragma unroll
            for (int j = 0; j < 8; ++j) {
                float sa = xc[i00] * w00 + xc[i01] * w01 +
                           xc[i10] * w10 + xc[i11] * w11;
                xc += HW_;
                float sb = xc[i00] * w00 + xc[i01] * w01 +
                           xc[i10] * w10 + xc[i11] * w11;
                xc += HW_;
                pk.u[j] = (unsigned)f2bf(sa) | ((unsigned)f2bf(sb) << 16);
            }
            char* base = samp + p_s * 128;
            int s  = (p_s & 7) << 4;
            int cb = cg * 32;
            *(uint4*)(base + (cb ^ s))        = pk.v[0];
            *(uint4*)(base + ((cb + 16) ^ s)) = pk.v[1];
        }
        __syncthreads();

        // ---- MFMA: 2 K-steps of 32 over this chunk's 64 channels ----
        #pragma unroll
        for (int ks = 0; ks < 2; ++ks) {
            int colb = ks * 64 + lg * 16;
            int ra0 = wr * 32 + lr, ra1 = ra0 + 16;
            int rb0 = wc * 32 + lr, rb1 = rb0 + 16;
            short8 a0 = *(const short8*)(wl   + ra0 * 128 + (colb ^ ((ra0 & 7) << 4)));
            short8 a1 = *(const short8*)(wl   + ra1 * 128 + (colb ^ ((ra1 & 7) << 4)));
            short8 b0 = *(const short8*)(samp + rb0 * 128 + (colb ^ ((rb0 & 7) << 4)));
            short8 b1 = *(const short8*)(samp + rb1 * 128 + (colb ^ ((rb1 & 7) << 4)));
            acc[0][0] = __builtin_amdgcn_mfma_f32_16x16x32_bf16(a0, b0, acc[0][0], 0, 0, 0);
            acc[0][1] = __builtin_amdgcn_mfma_f32_16x16x32_bf16(a0, b1, acc[0][1], 0, 0, 0);
            acc[1][0] = __builtin_amdgcn_mfma_f32_16x16x32_bf16(a1, b0, acc[1][0], 0, 0, 0);
            acc[1][1] = __builtin_amdgcn_mfma_f32_16x16x32_bf16(a1, b1, acc[1][1], 0, 0, 0);
        }
    }

    // ---- epilogue: C/D layout col=lane&15, row=(lane>>4)*4+reg ----
    #pragma unroll
    for (int m = 0; m < 2; ++m) {
        int ob = wr * 32 + m * 16 + lg * 4;
        #pragma unroll
        for (int n = 0; n < 2; ++n) {
            int p = pixbase + wc * 32 + n * 16 + lr;
            #pragma unroll
            for (int r = 0; r < 4; ++r) {
                int o = ob + r;
                out[((size_t)bi * O_ + o) * HW_ + p] = acc[m][n][r] + bias[o];
            }
        }
    }
}

extern "C" void kernel_launch(void* const* d_in, const int* in_sizes, int n_in,
                              void* d_out, int out_size, void* d_ws, size_t ws_size,
                              hipStream_t stream)
{
    const float* x    = (const float*)d_in[0];
    const float* offs = (const float*)d_in[1];
    const float* mask = (const float*)d_in[2];
    const float* wgt  = (const float*)d_in[3];
    const float* bias = (const float*)d_in[4];
    float* out = (float*)d_out;
    unsigned short* wsb = (unsigned short*)d_ws;    // 9*64*64 bf16 = 73728 B

    hipLaunchKernelGGL(cvt_w_kernel, dim3(16), dim3(256), 0, stream, wgt, wsb);
    hipLaunchKernelGGL(dcn_mfma, dim3(B_ * NTILE), dim3(256), 0, stream,
                       x, offs, mask, wsb, bias, out);
}

// Round 3
// 199.614 us; speedup vs baseline: 1.3028x; 1.0188x over previous
//
#include <hip/hip_runtime.h>

// Modulated deformable conv (DCNv2) fwd — bf16-MFMA fused, XCD-pinned.
// B=8, C=64, H=W=96, O=64, K=3, stride=1, pad=1, dil=1, DG=1 -> Ho=Wo=96.
// KEY: blockIdx % 8 == XCD id (round-robin dispatch). bi = blockIdx & 7 pins
// each batch image to one XCD; its x-image (2.36 MB) + offs/mask stay
// L2-resident (4 MB/XCD), killing the 21x HBM over-fetch seen in R2.

#define B_   8
#define C_   64
#define H_   96
#define W_   96
#define O_   64
#define KK_  9
#define HW_  (H_ * W_)          // 9216
#define PIXB 64
#define NTILE (HW_ / PIXB)      // 144

typedef __attribute__((ext_vector_type(8))) short short8;   // 8 bf16 = 4 VGPR
typedef __attribute__((ext_vector_type(4))) float f32x4;

__device__ __forceinline__ unsigned short f2bf(float f) {
    union { float f; unsigned u; } v; v.f = f;
    unsigned r = v.u + 0x7FFF + ((v.u >> 16) & 1);   // RNE
    return (unsigned short)(r >> 16);
}

// ---- pre-kernel: weights fp32 [O][C][KK] -> bf16 ws [kk][o][c] ----
__global__ void cvt_w_kernel(const float* __restrict__ wgt,
                             unsigned short* __restrict__ wsb) {
    int i = blockIdx.x * 256 + threadIdx.x;          // (o,c)
    if (i < O_ * C_) {
        int o = i >> 6, c = i & 63;
        #pragma unroll
        for (int kk = 0; kk < KK_; ++kk)
            wsb[kk * (O_ * C_) + o * C_ + c] =
                f2bf(wgt[(size_t)(o * C_ + c) * KK_ + kk]);
    }
}

// LDS: samp 8192 B ([64 px][128 B bf16, XOR-swz]) | wl 8192 B ([64 o][128 B])
//      coords 11520 B; epilogue aliases samp/wl+coords as [64][65] f32.
__global__ __launch_bounds__(256, 5)
void dcn_mfma(const float* __restrict__ x, const float* __restrict__ offs,
              const float* __restrict__ mask,
              const unsigned short* __restrict__ wsb,
              const float* __restrict__ bias, float* __restrict__ out)
{
    __shared__ __align__(16) char lds[27904];
    char*  samp = lds;                       // 8192
    char*  wl   = lds + 8192;                // 8192
    float* c_ly = (float*)(lds + 16384);
    float* c_lx = c_ly + 576;
    float* c_mv = c_lx + 576;
    int*   c_y0 = (int*)(c_mv + 576);
    int*   c_x0 = c_y0 + 576;

    const int t    = threadIdx.x;
    const int lane = t & 63;
    const int wid  = t >> 6;
    // XCD-pinned mapping: image = XCD (blockIdx % 8 is the XCD round-robin)
    const int bi   = blockIdx.x & 7;
    const int tile = blockIdx.x >> 3;
    const int pixbase = tile * PIXB;

    // ---- phase 1: sampling coords for (kk, p): 576 entries ----
    #pragma unroll
    for (int r = 0; r < 3; ++r) {
        int i = t + 256 * r;
        if (i < KK_ * PIXB) {
            int kk = i >> 6, p = i & 63;
            int pix = pixbase + p;
            int ho = pix / W_, wo = pix % W_;
            float offy = offs[((size_t)bi * 18 + 2 * kk + 0) * HW_ + pix];
            float offx = offs[((size_t)bi * 18 + 2 * kk + 1) * HW_ + pix];
            float mv   = mask[((size_t)bi * 9 + kk) * HW_ + pix];
            float py = (float)(ho - 1 + kk / 3) + offy;
            float px = (float)(wo - 1 + kk % 3) + offx;
            float y0f = floorf(py), x0f = floorf(px);
            c_ly[i] = py - y0f;
            c_lx[i] = px - x0f;
            c_mv[i] = mv;
            c_y0[i] = (int)y0f;
            c_x0[i] = (int)x0f;
        }
    }

    f32x4 acc[2][2] = {};
    const int wr = wid >> 1, wc = wid & 1;     // wave -> (o half, px half)
    const int lr = lane & 15, lg = lane >> 4;

    const float* xb  = x + (size_t)bi * C_ * HW_;
    const int p_s = lane;                       // this thread's sample pixel
    const int cg  = wid;                        // channel group: cg*16..+15
    const float* xc0 = xb + (size_t)cg * 16 * HW_;

    for (int kk = 0; kk < KK_; ++kk) {
        __syncthreads();   // coords ready (kk==0) / prev chunk consumed

        // ---- stage W chunk kk: [o][c] bf16, swizzled ----
        {
            int o = t >> 2, cq = (t & 3) * 16;  // 16 bf16 = 32 B per thread
            const uint4* g = (const uint4*)(wsb + (size_t)kk * (O_ * C_)
                                            + o * C_ + cq);
            uint4 w0 = g[0], w1 = g[1];
            char* base = wl + o * 128;
            int s = (o & 7) << 4;
            *(uint4*)(base + ((cq * 2) ^ s))      = w0;
            *(uint4*)(base + ((cq * 2 + 16) ^ s)) = w1;
        }

        // ---- sample 16 channels of pixel p_s, pack bf16, swizzled write ----
        {
            int ci = kk * 64 + p_s;
            float ly = c_ly[ci], lx = c_lx[ci], mv = c_mv[ci];
            int y0 = c_y0[ci], x0 = c_x0[ci];
            int y1 = y0 + 1, x1 = x0 + 1;
            float hy = 1.f - ly, hx = 1.f - lx;
            bool oky0 = (y0 >= 0) & (y0 < H_), oky1 = (y1 >= 0) & (y1 < H_);
            bool okx0 = (x0 >= 0) & (x0 < W_), okx1 = (x1 >= 0) & (x1 < W_);
            float w00 = hy * hx * mv * ((oky0 & okx0) ? 1.f : 0.f);
            float w01 = hy * lx * mv * ((oky0 & okx1) ? 1.f : 0.f);
            float w10 = ly * hx * mv * ((oky1 & okx0) ? 1.f : 0.f);
            float w11 = ly * lx * mv * ((oky1 & okx1) ? 1.f : 0.f);
            int iy0 = min(max(y0, 0), H_ - 1), iy1 = min(max(y1, 0), H_ - 1);
            int ix0 = min(max(x0, 0), W_ - 1), ix1 = min(max(x1, 0), W_ - 1);
            int i00 = iy0 * W_ + ix0, i01 = iy0 * W_ + ix1;
            int i10 = iy1 * W_ + ix0, i11 = iy1 * W_ + ix1;

            union { unsigned u[8]; uint4 v[2]; } pk;
            const float* xc = xc0;
            #pragma unroll
            for (int j = 0; j < 8; ++j) {
                float sa = xc[i00] * w00 + xc[i01] * w01 +
                           xc[i10] * w10 + xc[i11] * w11;
                xc += HW_;
                float sb = xc[i00] * w00 + xc[i01] * w01 +
                           xc[i10] * w10 + xc[i11] * w11;
                xc += HW_;
                pk.u[j] = (unsigned)f2bf(sa) | ((unsigned)f2bf(sb) << 16);
            }
            char* base = samp + p_s * 128;
            int s  = (p_s & 7) << 4;
            int cb = cg * 32;
            *(uint4*)(base + (cb ^ s))        = pk.v[0];
            *(uint4*)(base + ((cb + 16) ^ s)) = pk.v[1];
        }
        __syncthreads();

        // ---- MFMA: 2 K-steps of 32 over this chunk's 64 channels ----
        #pragma unroll
        for (int ks = 0; ks < 2; ++ks) {
            int colb = ks * 64 + lg * 16;
            int ra0 = wr * 32 + lr, ra1 = ra0 + 16;
            int rb0 = wc * 32 + lr, rb1 = rb0 + 16;
            short8 a0 = *(const short8*)(wl   + ra0 * 128 + (colb ^ ((ra0 & 7) << 4)));
            short8 a1 = *(const short8*)(wl   + ra1 * 128 + (colb ^ ((ra1 & 7) << 4)));
            short8 b0 = *(const short8*)(samp + rb0 * 128 + (colb ^ ((rb0 & 7) << 4)));
            short8 b1 = *(const short8*)(samp + rb1 * 128 + (colb ^ ((rb1 & 7) << 4)));
            acc[0][0] = __builtin_amdgcn_mfma_f32_16x16x32_bf16(a0, b0, acc[0][0], 0, 0, 0);
            acc[0][1] = __builtin_amdgcn_mfma_f32_16x16x32_bf16(a0, b1, acc[0][1], 0, 0, 0);
            acc[1][0] = __builtin_amdgcn_mfma_f32_16x16x32_bf16(a1, b0, acc[1][0], 0, 0, 0);
            acc[1][1] = __builtin_amdgcn_mfma_f32_16x16x32_bf16(a1, b1, acc[1][1], 0, 0, 0);
        }
    }

    // ---- epilogue: LDS transpose -> full-line coalesced stores ----
    // (R0's pattern: WRITE_SIZE was exactly 18.4 MB; direct MFMA-layout
    //  stores in R2 doubled it to 38 MB via 64 B partial-line writes.)
    __syncthreads();
    float* outb = (float*)lds;              // [64 o][65 f32] = 16640 B
    #pragma unroll
    for (int m = 0; m < 2; ++m) {
        int ob = wr * 32 + m * 16 + lg * 4;
        #pragma unroll
        for (int n = 0; n < 2; ++n) {
            int p = wc * 32 + n * 16 + lr;
            #pragma unroll
            for (int r = 0; r < 4; ++r)
                outb[(ob + r) * 65 + p] = acc[m][n][r];
        }
    }
    __syncthreads();
    #pragma unroll
    for (int r = 0; r < 16; ++r) {
        int idx = t + 256 * r;              // 4096 outputs
        int o = idx >> 6, p = idx & 63;
        out[((size_t)bi * O_ + o) * HW_ + pixbase + p] = outb[o * 65 + p] + bias[o];
    }
}

extern "C" void kernel_launch(void* const* d_in, const int* in_sizes, int n_in,
                              void* d_out, int out_size, void* d_ws, size_t ws_size,
                              hipStream_t stream)
{
    const float* x    = (const float*)d_in[0];
    const float* offs = (const float*)d_in[1];
    const float* mask = (const float*)d_in[2];
    const float* wgt  = (const float*)d_in[3];
    const float* bias = (const float*)d_in[4];
    float* out = (float*)d_out;
    unsigned short* wsb = (unsigned short*)d_ws;    // 9*64*64 bf16 = 73728 B

    hipLaunchKernelGGL(cvt_w_kernel, dim3(16), dim3(256), 0, stream, wgt, wsb);
    hipLaunchKernelGGL(dcn_mfma, dim3(B_ * NTILE), dim3(256), 0, stream,
                       x, offs, mask, wsb, bias, out);
}

// Round 4
// 65.954 us; speedup vs baseline: 3.9429x; 3.0266x over previous
//
#include <hip/hip_runtime.h>

// DCNv2 fwd — bf16-MFMA, NHWC-bf16 pre-transposed x to kill scattered-gather
// address count (R3 diagnosis: 170M scalar gather lane-addrs = TA-bound).
// B=8, C=64, H=W=96, O=64, K=3, s=1, p=1, d=1, DG=1 -> Ho=Wo=96.

#define B_   8
#define C_   64
#define H_   96
#define W_   96
#define O_   64
#define KK_  9
#define HW_  (H_ * W_)          // 9216
#define PIXB 64
#define NTILE (HW_ / PIXB)      // 144

typedef __attribute__((ext_vector_type(8))) short short8;   // 8 bf16
typedef __attribute__((ext_vector_type(4))) float f32x4;

__device__ __forceinline__ unsigned short f2bf(float f) {
    union { float f; unsigned u; } v; v.f = f;
    unsigned r = v.u + 0x7FFF + ((v.u >> 16) & 1);   // RNE
    return (unsigned short)(r >> 16);
}
__device__ __forceinline__ float bflo(unsigned u) {
    union { unsigned u; float f; } v; v.u = u << 16; return v.f;
}
__device__ __forceinline__ float bfhi(unsigned u) {
    union { unsigned u; float f; } v; v.u = u & 0xffff0000u; return v.f;
}
__device__ __forceinline__ unsigned packbf(float lo, float hi) {
    return (unsigned)f2bf(lo) | ((unsigned)f2bf(hi) << 16);
}

// ---- pre-kernel 1: x fp32 NCHW -> bf16 NHWC (pixel row = 64ch*2B = 1 line) ----
__global__ __launch_bounds__(256)
void cvt_x_kernel(const float* __restrict__ x, unsigned short* __restrict__ xT)
{
    __shared__ unsigned short tile[64][72];   // stride 144 B (16B-aligned rows)
    const int b  = blockIdx.x / NTILE;
    const int p0 = (blockIdx.x % NTILE) * 64;
    const int t  = threadIdx.x;
    #pragma unroll
    for (int r = 0; r < 16; ++r) {
        int idx = t + 256 * r;                // 4096 = 64c x 64p
        int c = idx >> 6, p = idx & 63;
        tile[p][c] = f2bf(x[((size_t)b * C_ + c) * HW_ + p0 + p]);
    }
    __syncthreads();
    #pragma unroll
    for (int r = 0; r < 2; ++r) {
        int idx = t + 256 * r;                // 512 chunks of 8 bf16 (16 B)
        int p = idx >> 3, cq = (idx & 7) * 8;
        uint4 v = *(const uint4*)&tile[p][cq];
        *(uint4*)(xT + ((size_t)b * HW_ + p0 + p) * C_ + cq) = v;
    }
}

// ---- pre-kernel 2: weights fp32 [O][C][KK] -> bf16 [kk][o][c] ----
__global__ void cvt_w_kernel(const float* __restrict__ wgt,
                             unsigned short* __restrict__ wsb) {
    int i = blockIdx.x * 256 + threadIdx.x;          // (o,c)
    if (i < O_ * C_) {
        int o = i >> 6, c = i & 63;
        #pragma unroll
        for (int kk = 0; kk < KK_; ++kk)
            wsb[kk * (O_ * C_) + o * C_ + c] =
                f2bf(wgt[(size_t)(o * C_ + c) * KK_ + kk]);
    }
}

// LDS: samp 8192 ([64 px][128 B bf16, XOR-swz]) | wl 8192 | coords 11520
__global__ __launch_bounds__(256, 4)
void dcn_mfma(const unsigned short* __restrict__ xT,
              const float* __restrict__ offs, const float* __restrict__ mask,
              const unsigned short* __restrict__ wsb,
              const float* __restrict__ bias, float* __restrict__ out)
{
    __shared__ __align__(16) char lds[27904];
    char*  samp = lds;                       // 8192
    char*  wl   = lds + 8192;                // 8192
    float* c_ly = (float*)(lds + 16384);
    float* c_lx = c_ly + 576;
    float* c_mv = c_lx + 576;
    int*   c_y0 = (int*)(c_mv + 576);
    int*   c_x0 = c_y0 + 576;

    const int t    = threadIdx.x;
    const int lane = t & 63;
    const int wid  = t >> 6;
    const int bi   = blockIdx.x & 7;          // XCD-pinned (keep R3's FETCH win)
    const int tile = blockIdx.x >> 3;
    const int pixbase = tile * PIXB;

    // ---- coords for (kk, p): 576 entries ----
    #pragma unroll
    for (int r = 0; r < 3; ++r) {
        int i = t + 256 * r;
        if (i < KK_ * PIXB) {
            int kk = i >> 6, p = i & 63;
            int pix = pixbase + p;
            int ho = pix / W_, wo = pix % W_;
            float offy = offs[((size_t)bi * 18 + 2 * kk + 0) * HW_ + pix];
            float offx = offs[((size_t)bi * 18 + 2 * kk + 1) * HW_ + pix];
            float mv   = mask[((size_t)bi * 9 + kk) * HW_ + pix];
            float py = (float)(ho - 1 + kk / 3) + offy;
            float px = (float)(wo - 1 + kk % 3) + offx;
            float y0f = floorf(py), x0f = floorf(px);
            c_ly[i] = py - y0f;
            c_lx[i] = px - x0f;
            c_mv[i] = mv;
            c_y0[i] = (int)y0f;
            c_x0[i] = (int)x0f;
        }
    }

    f32x4 acc[2][2] = {};
    const int wr = wid >> 1, wc = wid & 1;
    const int lr = lane & 15, lg = lane >> 4;

    const int p_s = lane;                     // sample pixel
    const int cg  = wid;                      // channel group (16 ch)
    const unsigned short* xb = xT + (size_t)bi * HW_ * C_ + cg * 16;

    for (int kk = 0; kk < KK_; ++kk) {
        __syncthreads();

        // ---- stage W chunk kk: [o][c] bf16, swizzled ----
        {
            int o = t >> 2, cq = (t & 3) * 16;
            const uint4* g = (const uint4*)(wsb + (size_t)kk * (O_ * C_)
                                            + o * C_ + cq);
            uint4 w0 = g[0], w1 = g[1];
            char* base = wl + o * 128;
            int s = (o & 7) << 4;
            *(uint4*)(base + ((cq * 2) ^ s))      = w0;
            *(uint4*)(base + ((cq * 2 + 16) ^ s)) = w1;
        }

        // ---- sample 16 ch of pixel p_s: 8 x dwordx4 from NHWC-bf16 ----
        {
            int ci = kk * 64 + p_s;
            float ly = c_ly[ci], lx = c_lx[ci], mv = c_mv[ci];
            int y0 = c_y0[ci], x0 = c_x0[ci];
            int y1 = y0 + 1, x1 = x0 + 1;
            float hy = 1.f - ly, hx = 1.f - lx;
            bool oky0 = (y0 >= 0) & (y0 < H_), oky1 = (y1 >= 0) & (y1 < H_);
            bool okx0 = (x0 >= 0) & (x0 < W_), okx1 = (x1 >= 0) & (x1 < W_);
            float w00 = hy * hx * mv * ((oky0 & okx0) ? 1.f : 0.f);
            float w01 = hy * lx * mv * ((oky0 & okx1) ? 1.f : 0.f);
            float w10 = ly * hx * mv * ((oky1 & okx0) ? 1.f : 0.f);
            float w11 = ly * lx * mv * ((oky1 & okx1) ? 1.f : 0.f);
            int iy0 = min(max(y0, 0), H_ - 1), iy1 = min(max(y1, 0), H_ - 1);
            int ix0 = min(max(x0, 0), W_ - 1), ix1 = min(max(x1, 0), W_ - 1);
            const uint4* a00 = (const uint4*)(xb + (size_t)(iy0 * W_ + ix0) * C_);
            const uint4* a01 = (const uint4*)(xb + (size_t)(iy0 * W_ + ix1) * C_);
            const uint4* a10 = (const uint4*)(xb + (size_t)(iy1 * W_ + ix0) * C_);
            const uint4* a11 = (const uint4*)(xb + (size_t)(iy1 * W_ + ix1) * C_);
            unsigned c0[8], c1[8], c2[8], c3[8];   // 16 ch per corner (8 u32)
            *(uint4*)&c0[0] = a00[0]; *(uint4*)&c0[4] = a00[1];
            *(uint4*)&c1[0] = a01[0]; *(uint4*)&c1[4] = a01[1];
            *(uint4*)&c2[0] = a10[0]; *(uint4*)&c2[4] = a10[1];
            *(uint4*)&c3[0] = a11[0]; *(uint4*)&c3[4] = a11[1];

            union { unsigned u[8]; uint4 v[2]; } pk;
            #pragma unroll
            for (int j = 0; j < 8; ++j) {
                float lo = fmaf(bflo(c0[j]), w00, fmaf(bflo(c1[j]), w01,
                           fmaf(bflo(c2[j]), w10, bflo(c3[j]) * w11)));
                float hi = fmaf(bfhi(c0[j]), w00, fmaf(bfhi(c1[j]), w01,
                           fmaf(bfhi(c2[j]), w10, bfhi(c3[j]) * w11)));
                pk.u[j] = packbf(lo, hi);
            }
            char* base = samp + p_s * 128;
            int s  = (p_s & 7) << 4;
            int cb = cg * 32;
            *(uint4*)(base + (cb ^ s))        = pk.v[0];
            *(uint4*)(base + ((cb + 16) ^ s)) = pk.v[1];
        }
        __syncthreads();

        // ---- MFMA: 2 K-steps of 32 over this chunk's 64 channels ----
        #pragma unroll
        for (int ks = 0; ks < 2; ++ks) {
            int colb = ks * 64 + lg * 16;
            int ra0 = wr * 32 + lr, ra1 = ra0 + 16;
            int rb0 = wc * 32 + lr, rb1 = rb0 + 16;
            short8 a0 = *(const short8*)(wl   + ra0 * 128 + (colb ^ ((ra0 & 7) << 4)));
            short8 a1 = *(const short8*)(wl   + ra1 * 128 + (colb ^ ((ra1 & 7) << 4)));
            short8 b0 = *(const short8*)(samp + rb0 * 128 + (colb ^ ((rb0 & 7) << 4)));
            short8 b1 = *(const short8*)(samp + rb1 * 128 + (colb ^ ((rb1 & 7) << 4)));
            acc[0][0] = __builtin_amdgcn_mfma_f32_16x16x32_bf16(a0, b0, acc[0][0], 0, 0, 0);
            acc[0][1] = __builtin_amdgcn_mfma_f32_16x16x32_bf16(a0, b1, acc[0][1], 0, 0, 0);
            acc[1][0] = __builtin_amdgcn_mfma_f32_16x16x32_bf16(a1, b0, acc[1][0], 0, 0, 0);
            acc[1][1] = __builtin_amdgcn_mfma_f32_16x16x32_bf16(a1, b1, acc[1][1], 0, 0, 0);
        }
    }

    // ---- epilogue: LDS transpose -> float4 full-line stores ----
    __syncthreads();
    float* outb = (float*)lds;               // [64 o][68 f32] = 17408 B
    #pragma unroll
    for (int m = 0; m < 2; ++m) {
        int ob = wr * 32 + m * 16 + lg * 4;
        #pragma unroll
        for (int n = 0; n < 2; ++n) {
            int p = wc * 32 + n * 16 + lr;
            #pragma unroll
            for (int r = 0; r < 4; ++r)
                outb[(ob + r) * 68 + p] = acc[m][n][r];
        }
    }
    __syncthreads();
    #pragma unroll
    for (int r = 0; r < 4; ++r) {
        int idx = t + 256 * r;               // 1024 float4 chunks
        int o = idx >> 4, pq = (idx & 15) * 4;
        float4 v = *(const float4*)&outb[o * 68 + pq];
        float bv = bias[o];
        v.x += bv; v.y += bv; v.z += bv; v.w += bv;
        *(float4*)&out[((size_t)bi * O_ + o) * HW_ + pixbase + pq] = v;
    }
}

extern "C" void kernel_launch(void* const* d_in, const int* in_sizes, int n_in,
                              void* d_out, int out_size, void* d_ws, size_t ws_size,
                              hipStream_t stream)
{
    const float* x    = (const float*)d_in[0];
    const float* offs = (const float*)d_in[1];
    const float* mask = (const float*)d_in[2];
    const float* wgt  = (const float*)d_in[3];
    const float* bias = (const float*)d_in[4];
    float* out = (float*)d_out;

    unsigned short* xT  = (unsigned short*)d_ws;                 // 9,437,184 B
    unsigned short* wsb = (unsigned short*)((char*)d_ws + 9437184); // 73,728 B

    hipLaunchKernelGGL(cvt_x_kernel, dim3(B_ * NTILE), dim3(256), 0, stream, x, xT);
    hipLaunchKernelGGL(cvt_w_kernel, dim3(16), dim3(256), 0, stream, wgt, wsb);
    hipLaunchKernelGGL(dcn_mfma, dim3(B_ * NTILE), dim3(256), 0, stream,
                       xT, offs, mask, wsb, bias, out);
}